// Round 3
// baseline (379.742 us; speedup 1.0000x reference)
//
#include <hip/hip_runtime.h>
#include <hip/hip_bf16.h>

// Problem constants
#define B_ROWS 16384
#define OBS_D  512
#define H_D    1024
#define N_AG   9

typedef __attribute__((ext_vector_type(8))) short short8;
typedef __attribute__((ext_vector_type(4))) float floatx4;

__device__ __forceinline__ float bf_raw_to_f(short u) {
  unsigned v = ((unsigned)(unsigned short)u) << 16;
  union { unsigned u; float f; } c; c.u = v; return c.f;
}

__device__ __forceinline__ unsigned short f_to_bf_raw(float f) {
  union { float f; unsigned u; } c; c.f = f;
  unsigned u = c.u;
  u = u + 0x7FFF + ((u >> 16) & 1);   // round-to-nearest-even
  return (unsigned short)(u >> 16);
}

// ---------------------------------------------------------------------------
// Mega-prep: one launch does obs cast, W1T, W2T, WH (heads weights fused +
// Wk1 fold), and bias2048/w2cat concat. Branch is block-uniform.
// Grid: [0,4096) obs cast | [4096,4608) W1T | [4608,5632) W2T |
//       [5632,7680) WH    | [7680,7688) vecs
// ---------------------------------------------------------------------------
__global__ __launch_bounds__(256) void prep_all(
    const float* __restrict__ obs,
    const float* __restrict__ W1, const float* __restrict__ W2,
    const float* __restrict__ Wc1, const float* __restrict__ Wt1,
    const float* __restrict__ Wk1,
    const float* __restrict__ bc1, const float* __restrict__ bt1,
    const float* __restrict__ bk1,
    const float* __restrict__ Wc2, const float* __restrict__ Wt2,
    const float* __restrict__ Wk2,
    unsigned short* __restrict__ obs_bf,
    unsigned short* __restrict__ W1T, unsigned short* __restrict__ W2T,
    unsigned short* __restrict__ WH,
    float* __restrict__ bias2048, float* __restrict__ w2cat) {
  __shared__ float t[32][33];
  const int bx  = blockIdx.x;
  const int tid = threadIdx.x;

  if (bx < 4096) {                       // obs fp32 -> bf16, 8 elems/thread
    int i = (bx * 256 + tid) * 8;
    float4 a = *(const float4*)(obs + i);
    float4 b = *(const float4*)(obs + i + 4);
    short8 o;
    o[0] = (short)f_to_bf_raw(a.x); o[1] = (short)f_to_bf_raw(a.y);
    o[2] = (short)f_to_bf_raw(a.z); o[3] = (short)f_to_bf_raw(a.w);
    o[4] = (short)f_to_bf_raw(b.x); o[5] = (short)f_to_bf_raw(b.y);
    o[6] = (short)f_to_bf_raw(b.z); o[7] = (short)f_to_bf_raw(b.w);
    *(short8*)(obs_bf + i) = o;
    return;
  }

  const int tx = tid & 31;
  const int ty = tid >> 5;   // 0..7

  if (bx < 4608) {                       // W1 [512,1024] -> W1T [1024,512]
    const int tt = bx - 4096;
    const int k0 = (tt & 15) * 32;
    const int n0 = (tt >> 4) * 32;
#pragma unroll
    for (int i = ty; i < 32; i += 8)
      t[i][tx] = W1[(size_t)(k0 + i) * 1024 + n0 + tx];
    __syncthreads();
#pragma unroll
    for (int i = ty; i < 32; i += 8)
      W1T[(size_t)(n0 + i) * 512 + k0 + tx] = f_to_bf_raw(t[tx][i]);
    return;
  }

  if (bx < 5632) {                       // W2 [1024,1024] -> W2T [1024,1024]
    const int tt = bx - 4608;
    const int k0 = (tt & 31) * 32;
    const int n0 = (tt >> 5) * 32;
#pragma unroll
    for (int i = ty; i < 32; i += 8)
      t[i][tx] = W2[(size_t)(k0 + i) * 1024 + n0 + tx];
    __syncthreads();
#pragma unroll
    for (int i = ty; i < 32; i += 8)
      W2T[(size_t)(n0 + i) * 1024 + k0 + tx] = f_to_bf_raw(t[tx][i]);
    return;
  }

  if (bx < 7680) {                       // WH [2048,1024] (Wc1|Wt1|Wk1-fold)^T
    const int tt = bx - 5632;
    const int k0 = (tt & 31) * 32;
    const int n0 = (tt >> 5) * 32;       // 0..2016, region-uniform per block
#pragma unroll
    for (int i = ty; i < 32; i += 8) {
      const int n = n0 + tx;
      float v;
      if (n0 < 512)
        v = Wc1[(size_t)(k0 + i) * 512 + n];
      else if (n0 < 1024)
        v = Wt1[(size_t)(k0 + i) * 512 + (n - 512)];
      else
        v = Wk1[(size_t)(k0 + i) * 1024 + (n - 1024)]
          + Wk1[(size_t)(k0 + i + 1024) * 1024 + (n - 1024)];
      t[i][tx] = v;
    }
    __syncthreads();
#pragma unroll
    for (int i = ty; i < 32; i += 8)
      WH[(size_t)(n0 + i) * 1024 + k0 + tx] = f_to_bf_raw(t[tx][i]);
    return;
  }

  {                                      // bias2048 / w2cat
    int n = (bx - 7680) * 256 + tid;
    float b, w;
    if (n < 512)       { b = bc1[n];        w = Wc2[n]; }
    else if (n < 1024) { b = bt1[n - 512];  w = Wt2[n - 512]; }
    else               { b = bk1[n - 1024]; w = Wk2[n - 1024]; }
    bias2048[n] = b;
    w2cat[n] = w;
  }
}

// ---------------------------------------------------------------------------
// GEMM v2: C[M,N] = relu(A[M,K] @ Bt[N,K]^T + bias), bf16 in/out, fp32 acc.
// - A staged via global_load_lds (width 16) into 8KB LDS, XOR-swizzled cols
//   to cut bank conflicts (col16 ^= row&3 on both staging and frag read).
// - B fragments read DIRECTLY from global (L2-resident weights) into
//   registers, ping-pong double-buffered one half-iteration ahead.
//   This halves LDS traffic (the measured bottleneck: 32KB/iter vs the
//   ~110 B/cyc/CU LDS ceiling) -> MfmaUtil ceiling ~2x.
// K % 64 == 0 required (512/1024 here).
// ---------------------------------------------------------------------------
__global__ __launch_bounds__(256) void gemm_bias_relu(
    const unsigned short* __restrict__ A,
    const unsigned short* __restrict__ Bt,
    const float* __restrict__ bias,
    unsigned short* __restrict__ C,
    int M, int N, int K) {
  __shared__ __align__(16) unsigned short As[128 * 32];   // 8 KB

  const int tid  = threadIdx.x;
  const int lane = tid & 63;
  const int wave = tid >> 6;
  const int m0 = blockIdx.x * 128;
  const int n0 = blockIdx.y * 128;
  const int wm = (wave & 1) * 64;
  const int wn = (wave >> 1) * 64;
  const int fr = lane & 15;
  const int fq = lane >> 4;

  floatx4 acc[4][4];
#pragma unroll
  for (int i = 0; i < 4; ++i)
#pragma unroll
    for (int j = 0; j < 4; ++j) acc[i][j] = (floatx4){0.f, 0.f, 0.f, 0.f};

  const size_t rowb = (size_t)K * 2;
  // A staging: wave stages chunks wave*2 and wave*2+1 (16 rows each)
  const int srow   = lane >> 2;
  const int scol16 = (lane & 3) ^ (srow & 3);     // XOR swizzle
  const char* ga0 = (const char*)A + (size_t)(m0 + wave * 32 + srow) * rowb + scol16 * 16;
  const char* ga1 = ga0 + 16 * rowb;
  char* la0 = (char*)As + (wave * 2) * 1024 + lane * 16;
  char* la1 = la0 + 1024;

  // B fragment base: lane covers row n0+wn+ni*16+fr, 16B at k-offset fq*16
  const char* gB = (const char*)Bt + (size_t)(n0 + wn + fr) * rowb + fq * 16;
  const size_t nstep = 16 * rowb;

  short8 b0[4], b1[4];
#pragma unroll
  for (int ni = 0; ni < 4; ++ni)
    b0[ni] = *(const short8*)(gB + (size_t)ni * nstep);
  gB += 64;

  for (int k0 = 0; k0 < K; k0 += 64) {
    // ---- half 1: compute with b0, prefetch b1 (k0+32) ----
    __builtin_amdgcn_global_load_lds((const __attribute__((address_space(1))) void*)ga0,
                                     (__attribute__((address_space(3))) void*)la0, 16, 0, 0);
    __builtin_amdgcn_global_load_lds((const __attribute__((address_space(1))) void*)ga1,
                                     (__attribute__((address_space(3))) void*)la1, 16, 0, 0);
    ga0 += 64; ga1 += 64;
    __syncthreads();
#pragma unroll
    for (int ni = 0; ni < 4; ++ni)
      b1[ni] = *(const short8*)(gB + (size_t)ni * nstep);
    gB += 64;
    {
      short8 af[4];
#pragma unroll
      for (int mi = 0; mi < 4; ++mi)
        af[mi] = *(const short8*)((const char*)As + (wm + mi * 16 + fr) * 64 + ((fq ^ (fr & 3)) * 16));
#pragma unroll
      for (int mi = 0; mi < 4; ++mi)
#pragma unroll
        for (int ni = 0; ni < 4; ++ni)
          acc[mi][ni] = __builtin_amdgcn_mfma_f32_16x16x32_bf16(af[mi], b0[ni], acc[mi][ni], 0, 0, 0);
    }
    __syncthreads();

    // ---- half 2: compute with b1, prefetch b0 (k0+64) ----
    __builtin_amdgcn_global_load_lds((const __attribute__((address_space(1))) void*)ga0,
                                     (__attribute__((address_space(3))) void*)la0, 16, 0, 0);
    __builtin_amdgcn_global_load_lds((const __attribute__((address_space(1))) void*)ga1,
                                     (__attribute__((address_space(3))) void*)la1, 16, 0, 0);
    ga0 += 64; ga1 += 64;
    __syncthreads();
    if (k0 + 64 < K) {
#pragma unroll
      for (int ni = 0; ni < 4; ++ni)
        b0[ni] = *(const short8*)(gB + (size_t)ni * nstep);
      gB += 64;
    }
    {
      short8 af[4];
#pragma unroll
      for (int mi = 0; mi < 4; ++mi)
        af[mi] = *(const short8*)((const char*)As + (wm + mi * 16 + fr) * 64 + ((fq ^ (fr & 3)) * 16));
#pragma unroll
      for (int mi = 0; mi < 4; ++mi)
#pragma unroll
        for (int ni = 0; ni < 4; ++ni)
          acc[mi][ni] = __builtin_amdgcn_mfma_f32_16x16x32_bf16(af[mi], b1[ni], acc[mi][ni], 0, 0, 0);
    }
    __syncthreads();
  }

  // Epilogue: C/D layout col=lane&15, row=(lane>>4)*4+reg
#pragma unroll
  for (int ni = 0; ni < 4; ++ni) {
    const int gn = n0 + wn + ni * 16 + fr;
    const float bv = bias[gn];
#pragma unroll
    for (int mi = 0; mi < 4; ++mi) {
#pragma unroll
      for (int r = 0; r < 4; ++r) {
        const int gm = m0 + wm + mi * 16 + fq * 4 + r;
        float v = acc[mi][ni][r] + bv;
        v = v > 0.f ? v : 0.f;
        C[(size_t)gm * N + gn] = f_to_bf_raw(v);
      }
    }
  }
}

// ---------------------------------------------------------------------------
// Fused heads GEMM v2: same core; epilogue folds relu+w2-dot and writes
// NON-ATOMIC partials: part[j][row], j = n_strip*2 + wave_half (j in [0,32)).
// j 0..7 -> coverage cols, 8..15 -> tracking, 16..31 -> cooperation.
// ---------------------------------------------------------------------------
__global__ __launch_bounds__(256) void gemm_heads_fused(
    const unsigned short* __restrict__ A,    // G [B,1024]
    const unsigned short* __restrict__ Bt,   // WH [2048,1024]
    const float* __restrict__ bias,          // bias2048
    const float* __restrict__ w2,            // w2cat
    float* __restrict__ part,                // [32][B_ROWS] fp32
    int M, int N, int K) {
  __shared__ __align__(16) unsigned short As[128 * 32];

  const int tid  = threadIdx.x;
  const int lane = tid & 63;
  const int wave = tid >> 6;
  const int m0 = blockIdx.x * 128;
  const int n0 = blockIdx.y * 128;
  const int wm = (wave & 1) * 64;
  const int wn = (wave >> 1) * 64;
  const int fr = lane & 15;
  const int fq = lane >> 4;

  floatx4 acc[4][4];
#pragma unroll
  for (int i = 0; i < 4; ++i)
#pragma unroll
    for (int j = 0; j < 4; ++j) acc[i][j] = (floatx4){0.f, 0.f, 0.f, 0.f};

  const size_t rowb = (size_t)K * 2;
  const int srow   = lane >> 2;
  const int scol16 = (lane & 3) ^ (srow & 3);
  const char* ga0 = (const char*)A + (size_t)(m0 + wave * 32 + srow) * rowb + scol16 * 16;
  const char* ga1 = ga0 + 16 * rowb;
  char* la0 = (char*)As + (wave * 2) * 1024 + lane * 16;
  char* la1 = la0 + 1024;

  const char* gB = (const char*)Bt + (size_t)(n0 + wn + fr) * rowb + fq * 16;
  const size_t nstep = 16 * rowb;

  short8 b0[4], b1[4];
#pragma unroll
  for (int ni = 0; ni < 4; ++ni)
    b0[ni] = *(const short8*)(gB + (size_t)ni * nstep);
  gB += 64;

  for (int k0 = 0; k0 < K; k0 += 64) {
    __builtin_amdgcn_global_load_lds((const __attribute__((address_space(1))) void*)ga0,
                                     (__attribute__((address_space(3))) void*)la0, 16, 0, 0);
    __builtin_amdgcn_global_load_lds((const __attribute__((address_space(1))) void*)ga1,
                                     (__attribute__((address_space(3))) void*)la1, 16, 0, 0);
    ga0 += 64; ga1 += 64;
    __syncthreads();
#pragma unroll
    for (int ni = 0; ni < 4; ++ni)
      b1[ni] = *(const short8*)(gB + (size_t)ni * nstep);
    gB += 64;
    {
      short8 af[4];
#pragma unroll
      for (int mi = 0; mi < 4; ++mi)
        af[mi] = *(const short8*)((const char*)As + (wm + mi * 16 + fr) * 64 + ((fq ^ (fr & 3)) * 16));
#pragma unroll
      for (int mi = 0; mi < 4; ++mi)
#pragma unroll
        for (int ni = 0; ni < 4; ++ni)
          acc[mi][ni] = __builtin_amdgcn_mfma_f32_16x16x32_bf16(af[mi], b0[ni], acc[mi][ni], 0, 0, 0);
    }
    __syncthreads();

    __builtin_amdgcn_global_load_lds((const __attribute__((address_space(1))) void*)ga0,
                                     (__attribute__((address_space(3))) void*)la0, 16, 0, 0);
    __builtin_amdgcn_global_load_lds((const __attribute__((address_space(1))) void*)ga1,
                                     (__attribute__((address_space(3))) void*)la1, 16, 0, 0);
    ga0 += 64; ga1 += 64;
    __syncthreads();
    if (k0 + 64 < K) {
#pragma unroll
      for (int ni = 0; ni < 4; ++ni)
        b0[ni] = *(const short8*)(gB + (size_t)ni * nstep);
      gB += 64;
    }
    {
      short8 af[4];
#pragma unroll
      for (int mi = 0; mi < 4; ++mi)
        af[mi] = *(const short8*)((const char*)As + (wm + mi * 16 + fr) * 64 + ((fq ^ (fr & 3)) * 16));
#pragma unroll
      for (int mi = 0; mi < 4; ++mi)
#pragma unroll
        for (int ni = 0; ni < 4; ++ni)
          acc[mi][ni] = __builtin_amdgcn_mfma_f32_16x16x32_bf16(af[mi], b1[ni], acc[mi][ni], 0, 0, 0);
    }
    __syncthreads();
  }

  // Epilogue: relu + w2 weight + reduce over this block's 64 cols per
  // wave-half; non-atomic partial write (unique (j,row) per writer).
  const int j = blockIdx.y * 2 + (wave >> 1);
  float w2v[4], bv[4];
#pragma unroll
  for (int ni = 0; ni < 4; ++ni) {
    const int gn = n0 + wn + ni * 16 + fr;
    w2v[ni] = w2[gn];
    bv[ni]  = bias[gn];
  }
#pragma unroll
  for (int mi = 0; mi < 4; ++mi) {
#pragma unroll
    for (int r = 0; r < 4; ++r) {
      float p = 0.f;
#pragma unroll
      for (int ni = 0; ni < 4; ++ni) {
        float v = acc[mi][ni][r] + bv[ni];
        v = v > 0.f ? v : 0.f;
        p += v * w2v[ni];
      }
      p += __shfl_xor(p, 1);
      p += __shfl_xor(p, 2);
      p += __shfl_xor(p, 4);
      p += __shfl_xor(p, 8);
      if (fr == 0) {
        const int gm = m0 + wm + mi * 16 + fq * 4 + r;
        part[(size_t)j * B_ROWS + gm] = p;
      }
    }
  }
}

// ---------------------------------------------------------------------------
// Final: sum partials, sigmoid, broadcast to out [3, B, 9]. 1 thread/row.
// ---------------------------------------------------------------------------
__global__ __launch_bounds__(256) void final_out(
    const float* __restrict__ part,
    const float* __restrict__ bc2, const float* __restrict__ bt2,
    const float* __restrict__ bk2, float* __restrict__ out) {
  const int row = blockIdx.x * 256 + threadIdx.x;
  float sc = 0.f, st = 0.f, sk = 0.f;
#pragma unroll
  for (int j = 0; j < 8; ++j)  sc += part[(size_t)j * B_ROWS + row];
#pragma unroll
  for (int j = 8; j < 16; ++j) st += part[(size_t)j * B_ROWS + row];
#pragma unroll
  for (int j = 16; j < 32; ++j) sk += part[(size_t)j * B_ROWS + row];
  const float cv = 1.f / (1.f + expf(-(sc + bc2[0])));
  const float tv = 1.f / (1.f + expf(-(st + bt2[0])));
  const float kv = 1.f / (1.f + expf(-(sk + bk2[0])));
  float* o0 = out + (size_t)row * N_AG;
  float* o1 = out + (size_t)(B_ROWS + row) * N_AG;
  float* o2 = out + (size_t)(2 * B_ROWS + row) * N_AG;
#pragma unroll
  for (int a = 0; a < N_AG; ++a) { o0[a] = cv; o1[a] = tv; o2[a] = kv; }
}

// ---------------------------------------------------------------------------
extern "C" void kernel_launch(void* const* d_in, const int* in_sizes, int n_in,
                              void* d_out, int out_size, void* d_ws, size_t ws_size,
                              hipStream_t stream) {
  const float* obs = (const float*)d_in[0];
  // d_in[1] agent_positions: unused (outputs don't depend on it)
  const float* W1  = (const float*)d_in[2];
  const float* b1  = (const float*)d_in[3];
  const float* W2  = (const float*)d_in[4];
  const float* b2  = (const float*)d_in[5];
  const float* Wc1 = (const float*)d_in[6];
  const float* bc1 = (const float*)d_in[7];
  const float* Wc2 = (const float*)d_in[8];
  const float* bc2 = (const float*)d_in[9];
  const float* Wt1 = (const float*)d_in[10];
  const float* bt1 = (const float*)d_in[11];
  const float* Wt2 = (const float*)d_in[12];
  const float* bt2 = (const float*)d_in[13];
  const float* Wk1 = (const float*)d_in[14];
  const float* bk1 = (const float*)d_in[15];
  const float* Wk2 = (const float*)d_in[16];
  const float* bk2 = (const float*)d_in[17];
  float* out = (float*)d_out;

  // Workspace layout (bytes). PART aliases obs_bf (disjoint lifetimes:
  // obs_bf lives prep->gemm1; PART lives heads->final).
  char* ws = (char*)d_ws;
  unsigned short* obs_bf  = (unsigned short*)(ws + 0);         // 16 MB
  float*          PART    = (float*)(ws + 0);                  // 2 MB (alias)
  unsigned short* W1T     = (unsigned short*)(ws + 16777216);  // 1 MB  [1024,512]
  unsigned short* W2T     = (unsigned short*)(ws + 17825792);  // 2 MB  [1024,1024]
  unsigned short* WH      = (unsigned short*)(ws + 19922944);  // 4 MB  [2048,1024]
  float*          bias2048= (float*)(ws + 24117248);           // 8 KB
  float*          w2cat   = (float*)(ws + 24125440);           // 8 KB
  unsigned short* G1      = (unsigned short*)(ws + 24330240);  // 32 MB
  unsigned short* G       = (unsigned short*)(ws + 57884672);  // 32 MB

  // One prep launch for everything
  prep_all<<<7688, 256, 0, stream>>>(obs, W1, W2, Wc1, Wt1, Wk1,
                                     bc1, bt1, bk1, Wc2, Wt2, Wk2,
                                     obs_bf, W1T, W2T, WH, bias2048, w2cat);

  // Trunk
  gemm_bias_relu<<<dim3(128, 8), 256, 0, stream>>>(obs_bf, W1T, b1, G1, B_ROWS, 1024, 512);
  gemm_bias_relu<<<dim3(128, 8), 256, 0, stream>>>(G1, W2T, b2, G, B_ROWS, 1024, 1024);

  // All three heads, one fused GEMM, non-atomic partials
  gemm_heads_fused<<<dim3(128, 16), 256, 0, stream>>>(G, WH, bias2048, w2cat, PART,
                                                      B_ROWS, 2048, 1024);

  // Reduce partials + sigmoid + broadcast
  final_out<<<B_ROWS / 256, 256, 0, stream>>>(PART, bc2, bt2, bk2, out);
}

// Round 4
// 282.443 us; speedup vs baseline: 1.3445x; 1.3445x over previous
//
#include <hip/hip_runtime.h>
#include <hip/hip_bf16.h>

// Problem constants
#define B_ROWS 16384
#define OBS_D  512
#define H_D    1024
#define N_AG   9

typedef __attribute__((ext_vector_type(8))) short short8;
typedef __attribute__((ext_vector_type(4))) float floatx4;

__device__ __forceinline__ unsigned short f_to_bf_raw(float f) {
  union { float f; unsigned u; } c; c.f = f;
  unsigned u = c.u;
  u = u + 0x7FFF + ((u >> 16) & 1);   // round-to-nearest-even
  return (unsigned short)(u >> 16);
}

// ---------------------------------------------------------------------------
// Mega-prep: obs cast, W1T, W2T, WH (heads weights fused + Wk1 fold),
// bias2048/w2cat concat. Branch is block-uniform.
// Grid: [0,4096) obs | [4096,4608) W1T | [4608,5632) W2T |
//       [5632,7680) WH | [7680,7688) vecs
// ---------------------------------------------------------------------------
__global__ __launch_bounds__(256) void prep_all(
    const float* __restrict__ obs,
    const float* __restrict__ W1, const float* __restrict__ W2,
    const float* __restrict__ Wc1, const float* __restrict__ Wt1,
    const float* __restrict__ Wk1,
    const float* __restrict__ bc1, const float* __restrict__ bt1,
    const float* __restrict__ bk1,
    const float* __restrict__ Wc2, const float* __restrict__ Wt2,
    const float* __restrict__ Wk2,
    unsigned short* __restrict__ obs_bf,
    unsigned short* __restrict__ W1T, unsigned short* __restrict__ W2T,
    unsigned short* __restrict__ WH,
    float* __restrict__ bias2048, float* __restrict__ w2cat) {
  __shared__ float t[32][33];
  const int bx  = blockIdx.x;
  const int tid = threadIdx.x;

  if (bx < 4096) {                       // obs fp32 -> bf16, 8 elems/thread
    int i = (bx * 256 + tid) * 8;
    float4 a = *(const float4*)(obs + i);
    float4 b = *(const float4*)(obs + i + 4);
    short8 o;
    o[0] = (short)f_to_bf_raw(a.x); o[1] = (short)f_to_bf_raw(a.y);
    o[2] = (short)f_to_bf_raw(a.z); o[3] = (short)f_to_bf_raw(a.w);
    o[4] = (short)f_to_bf_raw(b.x); o[5] = (short)f_to_bf_raw(b.y);
    o[6] = (short)f_to_bf_raw(b.z); o[7] = (short)f_to_bf_raw(b.w);
    *(short8*)(obs_bf + i) = o;
    return;
  }

  const int tx = tid & 31;
  const int ty = tid >> 5;   // 0..7

  if (bx < 4608) {                       // W1 [512,1024] -> W1T [1024,512]
    const int tt = bx - 4096;
    const int k0 = (tt & 15) * 32;
    const int n0 = (tt >> 4) * 32;
#pragma unroll
    for (int i = ty; i < 32; i += 8)
      t[i][tx] = W1[(size_t)(k0 + i) * 1024 + n0 + tx];
    __syncthreads();
#pragma unroll
    for (int i = ty; i < 32; i += 8)
      W1T[(size_t)(n0 + i) * 512 + k0 + tx] = f_to_bf_raw(t[tx][i]);
    return;
  }

  if (bx < 5632) {                       // W2 [1024,1024] -> W2T [1024,1024]
    const int tt = bx - 4608;
    const int k0 = (tt & 31) * 32;
    const int n0 = (tt >> 5) * 32;
#pragma unroll
    for (int i = ty; i < 32; i += 8)
      t[i][tx] = W2[(size_t)(k0 + i) * 1024 + n0 + tx];
    __syncthreads();
#pragma unroll
    for (int i = ty; i < 32; i += 8)
      W2T[(size_t)(n0 + i) * 1024 + k0 + tx] = f_to_bf_raw(t[tx][i]);
    return;
  }

  if (bx < 7680) {                       // WH [2048,1024] (Wc1|Wt1|Wk1-fold)^T
    const int tt = bx - 5632;
    const int k0 = (tt & 31) * 32;
    const int n0 = (tt >> 5) * 32;       // region-uniform per block
#pragma unroll
    for (int i = ty; i < 32; i += 8) {
      const int n = n0 + tx;
      float v;
      if (n0 < 512)
        v = Wc1[(size_t)(k0 + i) * 512 + n];
      else if (n0 < 1024)
        v = Wt1[(size_t)(k0 + i) * 512 + (n - 512)];
      else
        v = Wk1[(size_t)(k0 + i) * 1024 + (n - 1024)]
          + Wk1[(size_t)(k0 + i + 1024) * 1024 + (n - 1024)];
      t[i][tx] = v;
    }
    __syncthreads();
#pragma unroll
    for (int i = ty; i < 32; i += 8)
      WH[(size_t)(n0 + i) * 1024 + k0 + tx] = f_to_bf_raw(t[tx][i]);
    return;
  }

  {                                      // bias2048 / w2cat
    int n = (bx - 7680) * 256 + tid;
    float b, w;
    if (n < 512)       { b = bc1[n];        w = Wc2[n]; }
    else if (n < 1024) { b = bt1[n - 512];  w = Wt2[n - 512]; }
    else               { b = bk1[n - 1024]; w = Wk2[n - 1024]; }
    bias2048[n] = b;
    w2cat[n] = w;
  }
}

// ===========================================================================
// GEMM core v3 (macro-ized body shared by both GEMM kernels):
//  - 128x128 block tile, BK=64, single-buffered 32KB LDS (A 16KB + B 16KB)
//    -> 2 barriers per 64-K (half of round-2's), 32 MFMAs per wave per iter.
//  - A and B staged via global_load_lds width=16. XOR swizzle on the GLOBAL
//    side (slot = chunk ^ (row&7)) so LDS rows (stride 128B = 32 banks) read
//    conflict-free (2 lanes/bank = free, m136); DMA dest stays contiguous.
//  - frag read: row r slot (c ^ (r&7)), c = ks*4 + fq.
// K % 64 == 0 (512 / 1024 here).
// ===========================================================================
#define GEMM_CORE_V3(ACC_DECL)                                                 \
  __shared__ __align__(16) unsigned short As[128 * 64];                        \
  __shared__ __align__(16) unsigned short Bs[128 * 64];                        \
  const int tid  = threadIdx.x;                                                \
  const int lane = tid & 63;                                                   \
  const int wave = tid >> 6;                                                   \
  const int m0 = blockIdx.x * 128;                                             \
  const int n0 = blockIdx.y * 128;                                             \
  const int wm = (wave & 1) * 64;                                              \
  const int wn = (wave >> 1) * 64;                                             \
  const int fr = lane & 15;                                                    \
  const int fq = lane >> 4;                                                    \
  ACC_DECL;                                                                    \
  const size_t rowb = (size_t)K * 2;                                           \
  const int srow8 = lane >> 3;               /* 0..7 row within 8-row chunk */ \
  const int scolx = (lane & 7) ^ srow8;      /* swizzled global 16B chunk   */ \
  const char* gA = (const char*)A + (size_t)(m0 + wave * 32 + srow8) * rowb    \
                   + scolx * 16;                                               \
  const char* gB = (const char*)Bt + (size_t)(n0 + wave * 32 + srow8) * rowb   \
                   + scolx * 16;                                               \
  char* lA = (char*)As + (wave * 32) * 128 + lane * 16;                        \
  char* lB = (char*)Bs + (wave * 32) * 128 + lane * 16;                        \
  const int fsA = (wm + fr) * 128;           /* frag base byte offsets */      \
  const int fsB = (wn + fr) * 128;                                             \
  const int fx7 = (fr & 7);                                                    \
  for (int k0 = 0; k0 < K; k0 += 64) {                                         \
    _Pragma("unroll")                                                          \
    for (int j = 0; j < 4; ++j) {                                              \
      __builtin_amdgcn_global_load_lds(                                        \
          (const __attribute__((address_space(1))) void*)(gA + (size_t)j * 8 * rowb), \
          (__attribute__((address_space(3))) void*)(lA + j * 1024), 16, 0, 0); \
      __builtin_amdgcn_global_load_lds(                                        \
          (const __attribute__((address_space(1))) void*)(gB + (size_t)j * 8 * rowb), \
          (__attribute__((address_space(3))) void*)(lB + j * 1024), 16, 0, 0); \
    }                                                                          \
    gA += 128; gB += 128;                                                      \
    __syncthreads();                                                           \
    short8 af[4][2], bf[4][2];                                                 \
    _Pragma("unroll")                                                          \
    for (int ks = 0; ks < 2; ++ks) {                                           \
      const int cA = ks * 4 + fq;                                              \
      const int slot = (cA ^ fx7) * 16;                                        \
      _Pragma("unroll")                                                        \
      for (int mi = 0; mi < 4; ++mi)                                           \
        af[mi][ks] = *(const short8*)((const char*)As + fsA + mi * 2048 + slot); \
      _Pragma("unroll")                                                        \
      for (int ni = 0; ni < 4; ++ni)                                           \
        bf[ni][ks] = *(const short8*)((const char*)Bs + fsB + ni * 2048 + slot); \
    }                                                                          \
    _Pragma("unroll")                                                          \
    for (int ks = 0; ks < 2; ++ks)                                             \
      _Pragma("unroll")                                                        \
      for (int mi = 0; mi < 4; ++mi)                                           \
        _Pragma("unroll")                                                      \
        for (int ni = 0; ni < 4; ++ni)                                         \
          acc[mi][ni] = __builtin_amdgcn_mfma_f32_16x16x32_bf16(               \
              af[mi][ks], bf[ni][ks], acc[mi][ni], 0, 0, 0);                   \
    __syncthreads();                                                           \
  }

#define ACC_INIT                                                               \
  floatx4 acc[4][4];                                                           \
  _Pragma("unroll")                                                            \
  for (int i = 0; i < 4; ++i)                                                  \
    _Pragma("unroll")                                                          \
    for (int j = 0; j < 4; ++j) acc[i][j] = (floatx4){0.f, 0.f, 0.f, 0.f}

// ---------------------------------------------------------------------------
// GEMM: C = relu(A @ Bt^T + bias), bf16 out
// ---------------------------------------------------------------------------
__global__ __launch_bounds__(256) void gemm_bias_relu(
    const unsigned short* __restrict__ A,
    const unsigned short* __restrict__ Bt,
    const float* __restrict__ bias,
    unsigned short* __restrict__ C,
    int M, int N, int K) {
  GEMM_CORE_V3(ACC_INIT)

  // Epilogue: C/D layout col=lane&15, row=(lane>>4)*4+reg
#pragma unroll
  for (int ni = 0; ni < 4; ++ni) {
    const int gn = n0 + wn + ni * 16 + fr;
    const float bv = bias[gn];
#pragma unroll
    for (int mi = 0; mi < 4; ++mi) {
#pragma unroll
      for (int r = 0; r < 4; ++r) {
        const int gm = m0 + wm + mi * 16 + fq * 4 + r;
        float v = acc[mi][ni][r] + bv;
        v = v > 0.f ? v : 0.f;
        C[(size_t)gm * N + gn] = f_to_bf_raw(v);
      }
    }
  }
}

// ---------------------------------------------------------------------------
// Fused heads GEMM: relu(G @ WH^T + bias2048) dotted with w2cat in-register,
// non-atomic partials part[j][row], j = blockIdx.y*2 + wave_half in [0,32).
// j 0..7 coverage, 8..15 tracking, 16..31 cooperation.
// ---------------------------------------------------------------------------
__global__ __launch_bounds__(256) void gemm_heads_fused(
    const unsigned short* __restrict__ A,    // G [B,1024]
    const unsigned short* __restrict__ Bt,   // WH [2048,1024]
    const float* __restrict__ bias,          // bias2048
    const float* __restrict__ w2,            // w2cat
    float* __restrict__ part,                // [32][B_ROWS]
    int M, int N, int K) {
  GEMM_CORE_V3(ACC_INIT)

  const int j = blockIdx.y * 2 + (wave >> 1);
  float w2v[4], bv[4];
#pragma unroll
  for (int ni = 0; ni < 4; ++ni) {
    const int gn = n0 + wn + ni * 16 + fr;
    w2v[ni] = w2[gn];
    bv[ni]  = bias[gn];
  }
#pragma unroll
  for (int mi = 0; mi < 4; ++mi) {
#pragma unroll
    for (int r = 0; r < 4; ++r) {
      float p = 0.f;
#pragma unroll
      for (int ni = 0; ni < 4; ++ni) {
        float v = acc[mi][ni][r] + bv[ni];
        v = v > 0.f ? v : 0.f;
        p += v * w2v[ni];
      }
      p += __shfl_xor(p, 1);
      p += __shfl_xor(p, 2);
      p += __shfl_xor(p, 4);
      p += __shfl_xor(p, 8);
      if (fr == 0) {
        const int gm = m0 + wm + mi * 16 + fq * 4 + r;
        part[(size_t)j * B_ROWS + gm] = p;
      }
    }
  }
}

// ---------------------------------------------------------------------------
// Final: sum partials, sigmoid, broadcast to out [3, B, 9]. 1 thread/row.
// ---------------------------------------------------------------------------
__global__ __launch_bounds__(256) void final_out(
    const float* __restrict__ part,
    const float* __restrict__ bc2, const float* __restrict__ bt2,
    const float* __restrict__ bk2, float* __restrict__ out) {
  const int row = blockIdx.x * 256 + threadIdx.x;
  float sc = 0.f, st = 0.f, sk = 0.f;
#pragma unroll
  for (int j = 0; j < 8; ++j)  sc += part[(size_t)j * B_ROWS + row];
#pragma unroll
  for (int j = 8; j < 16; ++j) st += part[(size_t)j * B_ROWS + row];
#pragma unroll
  for (int j = 16; j < 32; ++j) sk += part[(size_t)j * B_ROWS + row];
  const float cv = 1.f / (1.f + expf(-(sc + bc2[0])));
  const float tv = 1.f / (1.f + expf(-(st + bt2[0])));
  const float kv = 1.f / (1.f + expf(-(sk + bk2[0])));
  float* o0 = out + (size_t)row * N_AG;
  float* o1 = out + (size_t)(B_ROWS + row) * N_AG;
  float* o2 = out + (size_t)(2 * B_ROWS + row) * N_AG;
#pragma unroll
  for (int a = 0; a < N_AG; ++a) { o0[a] = cv; o1[a] = tv; o2[a] = kv; }
}

// ---------------------------------------------------------------------------
extern "C" void kernel_launch(void* const* d_in, const int* in_sizes, int n_in,
                              void* d_out, int out_size, void* d_ws, size_t ws_size,
                              hipStream_t stream) {
  const float* obs = (const float*)d_in[0];
  // d_in[1] agent_positions: unused (outputs don't depend on it)
  const float* W1  = (const float*)d_in[2];
  const float* b1  = (const float*)d_in[3];
  const float* W2  = (const float*)d_in[4];
  const float* b2  = (const float*)d_in[5];
  const float* Wc1 = (const float*)d_in[6];
  const float* bc1 = (const float*)d_in[7];
  const float* Wc2 = (const float*)d_in[8];
  const float* bc2 = (const float*)d_in[9];
  const float* Wt1 = (const float*)d_in[10];
  const float* bt1 = (const float*)d_in[11];
  const float* Wt2 = (const float*)d_in[12];
  const float* bt2 = (const float*)d_in[13];
  const float* Wk1 = (const float*)d_in[14];
  const float* bk1 = (const float*)d_in[15];
  const float* Wk2 = (const float*)d_in[16];
  const float* bk2 = (const float*)d_in[17];
  float* out = (float*)d_out;

  // Workspace layout. PART aliases obs_bf (disjoint lifetimes).
  char* ws = (char*)d_ws;
  unsigned short* obs_bf  = (unsigned short*)(ws + 0);         // 16 MB
  float*          PART    = (float*)(ws + 0);                  // 2 MB (alias)
  unsigned short* W1T     = (unsigned short*)(ws + 16777216);  // 1 MB  [1024,512]
  unsigned short* W2T     = (unsigned short*)(ws + 17825792);  // 2 MB  [1024,1024]
  unsigned short* WH      = (unsigned short*)(ws + 19922944);  // 4 MB  [2048,1024]
  float*          bias2048= (float*)(ws + 24117248);           // 8 KB
  float*          w2cat   = (float*)(ws + 24125440);           // 8 KB
  unsigned short* G1      = (unsigned short*)(ws + 24330240);  // 32 MB
  unsigned short* G       = (unsigned short*)(ws + 57884672);  // 32 MB

  prep_all<<<7688, 256, 0, stream>>>(obs, W1, W2, Wc1, Wt1, Wk1,
                                     bc1, bt1, bk1, Wc2, Wt2, Wk2,
                                     obs_bf, W1T, W2T, WH, bias2048, w2cat);

  gemm_bias_relu<<<dim3(128, 8), 256, 0, stream>>>(obs_bf, W1T, b1, G1, B_ROWS, 1024, 512);
  gemm_bias_relu<<<dim3(128, 8), 256, 0, stream>>>(G1, W2T, b2, G, B_ROWS, 1024, 1024);

  gemm_heads_fused<<<dim3(128, 16), 256, 0, stream>>>(G, WH, bias2048, w2cat, PART,
                                                      B_ROWS, 2048, 1024);

  final_out<<<B_ROWS / 256, 256, 0, stream>>>(PART, bc2, bt2, bk2, out);
}